// Round 11
// baseline (247.512 us; speedup 1.0000x reference)
//
#include <hip/hip_runtime.h>
#include <hip/hip_bf16.h>
#include <math.h>

#define NN 4096
#define EE 131072
#define EP (EE + NN)     // 135168 edges incl. self loops
#define C1 512
#define H1 8
#define C2 256
#define NWORDS 128       // 4096 bits / 32
#define KP 520           // padded K stride for bf16 split buffers (mult of 8)
#define LSTR 40          // LDS row stride in shorts (BK=32 + 8 pad -> 2-way conflicts only)

typedef __attribute__((ext_vector_type(8))) short bf16x8;
typedef __attribute__((ext_vector_type(4))) float f32x4;

__device__ __forceinline__ float wredMaxf(float v){
#pragma unroll
  for(int o=32;o;o>>=1) v = fmaxf(v, __shfl_xor(v,o));
  return v;
}
__device__ __forceinline__ float wredSumf(float v){
#pragma unroll
  for(int o=32;o;o>>=1) v += __shfl_xor(v,o);
  return v;
}
__device__ __forceinline__ int wredSumi(int v){
#pragma unroll
  for(int o=32;o;o>>=1) v += __shfl_xor(v,o);
  return v;
}

__device__ __forceinline__ void bfsplit(float v, unsigned short& h, unsigned short& l){
  unsigned bits = __float_as_uint(v);
  h = (unsigned short)(bits>>16);
  float hf = __uint_as_float(bits & 0xFFFF0000u);
  float lo = v - hf;                       // exact
  l = (unsigned short)(__float_as_uint(lo)>>16);
}

__device__ __forceinline__ unsigned short f2bf_rne(float v){
  unsigned b = __float_as_uint(v);
  return (unsigned short)((b + 0x7FFFu + ((b>>16)&1u)) >> 16);
}

// int64 edge_index => high words of first 8 entries are all zero.
__device__ __forceinline__ int detect_mode(const int* __restrict__ ei32){
  unsigned nz = 0;
#pragma unroll
  for(int i=1;i<16;i+=2) nz |= (unsigned)ei32[i];
  return nz != 0;   // 1 => int32, 0 => int64
}

__device__ __forceinline__ void edge_sd(const int* ei32, int mode, int e, int& s, int& d){
  if(e < EE){
    if(mode==0){ s = ei32[2*e]; d = ei32[2*(EE+e)]; }
    else       { s = ei32[e];   d = ei32[EE+e]; }
  } else { s = e - EE; d = s; }
}

// blocks 0..527: edge bitmaps+counts; 528..1551: cvtA; 1552..2575: cvtB (all independent)
__global__ __launch_bounds__(256) void k_build_cvt(const int* __restrict__ ei32,
    unsigned* __restrict__ rowbits, unsigned* __restrict__ colbits, unsigned* __restrict__ cnt,
    const float* __restrict__ X, unsigned short* __restrict__ xh, unsigned short* __restrict__ xl,
    const float* __restrict__ W1f, const float* __restrict__ W2f, const float* __restrict__ Wrf,
    unsigned short* __restrict__ b1h, unsigned short* __restrict__ b1l,
    unsigned short* __restrict__ b2h, unsigned short* __restrict__ b2l){
  int b = blockIdx.x, t = threadIdx.x;
  if(b < 528){
    int e = b*256 + t;
    if(e >= EP) return;
    int m = detect_mode(ei32), s, d;
    edge_sd(ei32, m, e, s, d);
    atomicOr(&rowbits[s*NWORDS + (d>>5)], 1u<<(d&31));
    atomicOr(&colbits[d*NWORDS + (s>>5)], 1u<<(s&31));
    atomicAdd(&cnt[d], 1u);
  } else if(b < 1552){
    int e = (b-528)*256 + t;
    int row = e >> 6;
    int c0 = (e & 63) * 8;
    const float4 v0 = *(const float4*)&X[(size_t)row*C1 + c0];
    const float4 v1q = *(const float4*)&X[(size_t)row*C1 + c0 + 4];
    float vv[8] = {v0.x,v0.y,v0.z,v0.w,v1q.x,v1q.y,v1q.z,v1q.w};
    unsigned short h[8], l[8];
#pragma unroll
    for(int j=0;j<8;j++) bfsplit(vv[j], h[j], l[j]);
    *(bf16x8*)&xh[(size_t)row*KP + c0] = *(bf16x8*)h;
    *(bf16x8*)&xl[(size_t)row*KP + c0] = *(bf16x8*)l;
  } else {
    int blk = b - 1552;
    const float* W; int N, n, nrow; unsigned short *bh, *bl;
    if(blk < 512){ W=W1f; N=512; n=blk;     nrow=n;     bh=b1h; bl=b1l; }
    else if(blk < 768){ W=W2f; N=256; n=blk-512; nrow=n;     bh=b2h; bl=b2l; }
    else { W=Wrf; N=256; n=blk-768; nrow=n+256; bh=b2h; bl=b2l; }
    int k = t*2;
    float a = W[(size_t)k*N + n];
    float bb = W[(size_t)(k+1)*N + n];
    unsigned short h0,l0,h1,l1;
    bfsplit(a,h0,l0); bfsplit(bb,h1,l1);
    unsigned short hp[2]={h0,h1}, lp[2]={l0,l1};
    *(unsigned int*)&bh[(size_t)nrow*KP + k] = *(unsigned int*)hp;
    *(unsigned int*)&bl[(size_t)nrow*KP + k] = *(unsigned int*)lp;
  }
}

// block 0: exclusive scan of cnt -> rowptr; blocks 1..1024: v1 = popc rows (distinct out-deg)
__global__ __launch_bounds__(256) void k_scan_deg(const unsigned* __restrict__ cnt, unsigned* __restrict__ rowptr,
    const unsigned* __restrict__ rowbits, float* __restrict__ v1){
  int t = threadIdx.x;
  if(blockIdx.x == 0){
    __shared__ unsigned part[256];
    unsigned loc[16]; unsigned s = 0;
#pragma unroll
    for(int i=0;i<16;i++){ loc[i]=cnt[t*16+i]; s+=loc[i]; }
    part[t]=s; __syncthreads();
    for(int off=1;off<256;off<<=1){
      unsigned v = (t>=off)? part[t-off] : 0u;
      __syncthreads();
      part[t]+=v;
      __syncthreads();
    }
    unsigned run = (t==0)? 0u : part[t-1];
#pragma unroll
    for(int i=0;i<16;i++){ rowptr[t*16+i]=run; run+=loc[i]; }
    if(t==255) rowptr[NN]=run;
  } else {
    int node = (blockIdx.x-1)*4 + (t>>6);
    int lane = t & 63;
    unsigned w0 = rowbits[node*NWORDS + 2*lane];
    unsigned w1 = rowbits[node*NWORDS + 2*lane + 1];
    int c = __popc(w0) + __popc(w1);
    c = wredSumi(c);
    if(lane==0) v1[node] = (float)c;
  }
}

// blocks 0..527: CSR fill; blocks 528..1551: v2 = A @ v1
__global__ __launch_bounds__(256) void k_fill_mv(const int* __restrict__ ei32,
    const unsigned* __restrict__ rowptr, unsigned* __restrict__ fill, unsigned* __restrict__ csr_src,
    const unsigned* __restrict__ rowbits, const float* __restrict__ v1, float* __restrict__ v2){
  int t = threadIdx.x;
  if(blockIdx.x < 528){
    int e = blockIdx.x*256 + t;
    if(e >= EP) return;
    int m = detect_mode(ei32), s, d;
    edge_sd(ei32, m, e, s, d);
    unsigned pos = rowptr[d] + atomicAdd(&fill[d], 1u);
    csr_src[pos]=(unsigned)s;
  } else {
    int node = (blockIdx.x-528)*4 + (t>>6);
    int lane = t & 63;
    float sum = 0.f;
    unsigned w = rowbits[node*NWORDS + 2*lane]; int b0 = lane*64;
    while(w){ int b=__ffs(w)-1; sum += v1[b0+b]; w &= w-1; }
    w = rowbits[node*NWORDS + 2*lane + 1]; b0 = lane*64 + 32;
    while(w){ int b=__ffs(w)-1; sum += v1[b0+b]; w &= w-1; }
    sum = wredSumf(sum);
    if(lane==0) v2[node] = sum;
  }
}

// v3 = A @ v2
__global__ __launch_bounds__(256) void k_mv2(const unsigned* __restrict__ rowbits,
    const float* __restrict__ v2, float* __restrict__ v3){
  int node = blockIdx.x*4 + (threadIdx.x>>6);
  int lane = threadIdx.x & 63;
  float sum = 0.f;
  unsigned w = rowbits[node*NWORDS + 2*lane]; int b0 = lane*64;
  while(w){ int b=__ffs(w)-1; sum += v2[b0+b]; w &= w-1; }
  w = rowbits[node*NWORDS + 2*lane + 1]; b0 = lane*64 + 32;
  while(w){ int b=__ffs(w)-1; sum += v2[b0+b]; w &= w-1; }
  sum = wredSumf(sum);
  if(lane==0) v3[node] = sum;
}

// ---- split-bf16 MFMA 64x64 tile body; K=512, BK=32 (20KB LDS -> 8 blocks/CU).
// amode=1: bf16 C (stride C1) + 8-head attn dots.  amode=2: cols<256 -> bf16 h2b (stride C2)
// + 1-head attn dots; cols>=256 -> f32 resf.
__device__ __forceinline__ void gemm_tile(unsigned short* lds, int bx, int by,
    const unsigned short* __restrict__ Ah, const unsigned short* __restrict__ Al,
    const unsigned short* __restrict__ Bh, const unsigned short* __restrict__ Bl,
    unsigned short* __restrict__ Cb, float* __restrict__ resf,
    const float* __restrict__ aS, const float* __restrict__ aD,
    float* __restrict__ oS, float* __restrict__ oD, int amode){
  unsigned short* Ahs = lds;             // [64][LSTR]
  unsigned short* Als = lds + 64*LSTR;
  unsigned short* Bhs = lds + 2*64*LSTR;
  unsigned short* Bls = lds + 3*64*LSTR;
  int bm = by*64, bn = bx*64;
  int t = threadIdx.x, lane = t&63, w = t>>6;
  int wm = (w>>1)*32, wn = (w&1)*32;
  f32x4 acc[2][2];
#pragma unroll
  for(int i=0;i<2;i++)
#pragma unroll
    for(int j=0;j<2;j++) acc[i][j] = (f32x4){0.f,0.f,0.f,0.f};
  int sm = t>>2, sk = (t&3)*8;           // each thread stages 8 shorts per matrix
  const unsigned short* pAh = &Ah[(size_t)(bm+sm)*KP + sk];
  const unsigned short* pAl = &Al[(size_t)(bm+sm)*KP + sk];
  const unsigned short* pBh = &Bh[(size_t)(bn+sm)*KP + sk];
  const unsigned short* pBl = &Bl[(size_t)(bn+sm)*KP + sk];
  int fr = lane&15, kg = lane>>4;
  bf16x8 rah = *(const bf16x8*)(pAh);
  bf16x8 ral = *(const bf16x8*)(pAl);
  bf16x8 rbh = *(const bf16x8*)(pBh);
  bf16x8 rbl = *(const bf16x8*)(pBl);
  *(bf16x8*)&Ahs[sm*LSTR+sk] = rah;
  *(bf16x8*)&Als[sm*LSTR+sk] = ral;
  *(bf16x8*)&Bhs[sm*LSTR+sk] = rbh;
  *(bf16x8*)&Bls[sm*LSTR+sk] = rbl;
  __syncthreads();
  for(int k0=0;k0<C1;k0+=32){
    int kn = k0+32;
    if(kn<C1){   // prefetch next K-tile into regs
      rah = *(const bf16x8*)(pAh+kn);
      ral = *(const bf16x8*)(pAl+kn);
      rbh = *(const bf16x8*)(pBh+kn);
      rbl = *(const bf16x8*)(pBl+kn);
    }
    bf16x8 fah[2], fal[2], fbh[2], fbl[2];
#pragma unroll
    for(int i=0;i<2;i++){
      fah[i] = *(bf16x8*)&Ahs[(wm + i*16 + fr)*LSTR + kg*8];
      fal[i] = *(bf16x8*)&Als[(wm + i*16 + fr)*LSTR + kg*8];
      fbh[i] = *(bf16x8*)&Bhs[(wn + i*16 + fr)*LSTR + kg*8];
      fbl[i] = *(bf16x8*)&Bls[(wn + i*16 + fr)*LSTR + kg*8];
    }
#pragma unroll
    for(int i=0;i<2;i++)
#pragma unroll
      for(int j=0;j<2;j++){
        acc[i][j] = __builtin_amdgcn_mfma_f32_16x16x32_bf16(fah[i], fbh[j], acc[i][j], 0,0,0);
        acc[i][j] = __builtin_amdgcn_mfma_f32_16x16x32_bf16(fah[i], fbl[j], acc[i][j], 0,0,0);
        acc[i][j] = __builtin_amdgcn_mfma_f32_16x16x32_bf16(fal[i], fbh[j], acc[i][j], 0,0,0);
      }
    __syncthreads();
    if(kn<C1){
      *(bf16x8*)&Ahs[sm*LSTR+sk] = rah;
      *(bf16x8*)&Als[sm*LSTR+sk] = ral;
      *(bf16x8*)&Bhs[sm*LSTR+sk] = rbh;
      *(bf16x8*)&Bls[sm*LSTR+sk] = rbl;
    }
    __syncthreads();
  }
#pragma unroll
  for(int i=0;i<2;i++)
#pragma unroll
    for(int j=0;j<2;j++){
      int gr = bm + wm + i*16 + kg*4;
      int gc = bn + wn + j*16 + fr;
      if(amode==1){
#pragma unroll
        for(int e=0;e<4;e++)
          Cb[(size_t)(gr+e)*C1 + gc] = f2bf_rne(acc[i][j][e]);
      } else {
        if(gc < 256){
#pragma unroll
          for(int e=0;e<4;e++)
            Cb[(size_t)(gr+e)*C2 + gc] = f2bf_rne(acc[i][j][e]);
        } else {
#pragma unroll
          for(int e=0;e<4;e++)
            resf[(size_t)(gr+e)*C2 + gc - 256] = acc[i][j][e];
        }
      }
    }
  bool do_attn = (amode==1) || (bn < 256);
  if(do_attn){
    float p1[2][4], p2[2][4];
#pragma unroll
    for(int i=0;i<2;i++)
#pragma unroll
      for(int e=0;e<4;e++){ p1[i][e]=0.f; p2[i][e]=0.f; }
#pragma unroll
    for(int j=0;j<2;j++){
      int col = bn + wn + j*16 + fr;
      float a1c = aS[col], a2c = aD[col];
#pragma unroll
      for(int i=0;i<2;i++)
#pragma unroll
        for(int e=0;e<4;e++){ p1[i][e] += acc[i][j][e]*a1c; p2[i][e] += acc[i][j][e]*a2c; }
    }
#pragma unroll
    for(int o=1;o<16;o<<=1){
#pragma unroll
      for(int i=0;i<2;i++)
#pragma unroll
        for(int e=0;e<4;e++){ p1[i][e]+=__shfl_xor(p1[i][e],o); p2[i][e]+=__shfl_xor(p2[i][e],o); }
    }
    if(fr==0){
      int head = (amode==1)? (bn>>6) : 0;
      int hs = (amode==1)? H1 : 1;
#pragma unroll
      for(int i=0;i<2;i++)
#pragma unroll
        for(int e=0;e<4;e++){
          int row = bm + wm + i*16 + kg*4 + e;
          atomicAdd(&oS[row*hs + head], p1[i][e]);
          atomicAdd(&oD[row*hs + head], p2[i][e]);
        }
    }
  }
}

// Fused: blocks 0..511 = GEMM1 (x@W1 -> hpre bf16, + attn1 dots);
// blocks 512..1535 = motif, ONE DST PER WAVE (4 dsts/block)
__global__ __launch_bounds__(256) void k_gemm1_motif(
    const unsigned short* __restrict__ Ah, const unsigned short* __restrict__ Al,
    const unsigned short* __restrict__ Bh, const unsigned short* __restrict__ Bl,
    unsigned short* __restrict__ hpreb, const float* __restrict__ as1, const float* __restrict__ ad1,
    float* __restrict__ asrc1, float* __restrict__ adst1,
    const unsigned* __restrict__ rowbits, const unsigned* __restrict__ colbits,
    const unsigned* __restrict__ rowptr, const unsigned* __restrict__ csr_src,
    const float* __restrict__ v3, float* __restrict__ mwc){
  __shared__ union {
    unsigned short g[4*64*LSTR];
    struct { unsigned short nbr[4][192]; int cntL[4]; } m;
  } sm;
  int b = blockIdx.x, t = threadIdx.x;
  if(b < 512){
    gemm_tile(sm.g, b&7, b>>3, Ah, Al, Bh, Bl, hpreb, nullptr,
              as1, ad1, asrc1, adst1, 1);
    return;
  }
  int lane = t&63, wv = t>>6;
  int d = (b-512)*4 + wv;
  if(lane==0) sm.m.cntL[wv]=0;
  // in-neighbor list (per-wave; DS ops within a wave are program-ordered)
  {
    unsigned w = colbits[d*NWORDS + 2*lane]; int b0 = lane*64;
    while(w){ int bb=__ffs(w)-1; int pos=atomicAdd(&sm.m.cntL[wv],1); sm.m.nbr[wv][pos]=(unsigned short)(b0+bb); w&=w-1; }
    w = colbits[d*NWORDS + 2*lane + 1]; b0 = lane*64 + 32;
    while(w){ int bb=__ffs(w)-1; int pos=atomicAdd(&sm.m.cntL[wv],1); sm.m.nbr[wv][pos]=(unsigned short)(b0+bb); w&=w-1; }
  }
  __syncthreads();
  int m = sm.m.cntL[wv];
  unsigned gp[8][2];
#pragma unroll
  for(int p=0;p<8;p++){ gp[p][0]=0u; gp[p][1]=0u; }
  for(int t0=0;t0<m;t0+=4){
    unsigned xa[4], xb[4];
#pragma unroll
    for(int j=0;j<4;j++){
      int tt=t0+j;
      if(tt<m){ int l = sm.m.nbr[wv][tt]; xa[j]=colbits[l*NWORDS+2*lane]; xb[j]=colbits[l*NWORDS+2*lane+1]; }
      else    { xa[j]=0u; xb[j]=0u; }
    }
#pragma unroll
    for(int j=0;j<4;j++){
      unsigned c = xa[j];
#pragma unroll
      for(int p=0;p<8;p++){ unsigned cy = gp[p][0] & c; gp[p][0] ^= c; c = cy; }
      c = xb[j];
#pragma unroll
      for(int p=0;p<8;p++){ unsigned cy = gp[p][1] & c; gp[p][1] ^= c; c = cy; }
    }
  }
  // edge phase: 4 edges/iter, packed 2x16-bit wave reduction (totals <= ~4600 < 2^16)
  unsigned base = rowptr[d], deg = rowptr[d+1]-base;
  for(unsigned i0=0;i0<deg;i0+=4){
    unsigned sidx[4], ra[4], rb[4];
#pragma unroll
    for(int j=0;j<4;j++){
      unsigned ii = (i0+j < deg) ? (i0+j) : (deg-1);
      sidx[j] = csr_src[base+ii];
    }
#pragma unroll
    for(int j=0;j<4;j++){ ra[j]=rowbits[sidx[j]*NWORDS+2*lane]; rb[j]=rowbits[sidx[j]*NWORDS+2*lane+1]; }
    int sum[4];
#pragma unroll
    for(int j=0;j<4;j++){
      int s=0;
#pragma unroll
      for(int p=0;p<8;p++)
        s += (__popc(ra[j]&gp[p][0]) + __popc(rb[j]&gp[p][1])) << p;
      sum[j]=s;
    }
    int pk0 = sum[0] | (sum[1]<<16);
    int pk1 = sum[2] | (sum[3]<<16);
    pk0 = wredSumi(pk0); pk1 = wredSumi(pk1);
    if(lane==0){
      int ss[4] = { pk0 & 0xFFFF, (pk0>>16)&0xFFFF, pk1 & 0xFFFF, (pk1>>16)&0xFFFF };
#pragma unroll
      for(int j=0;j<4;j++){
        unsigned idx = i0+j;
        if(idx<deg)
          mwc[base+idx] = (float)ss[j] / fmaxf(v3[csr_src[base+idx]], 1.0f);
      }
    }
  }
}

// GEMM2 standalone: h1 @ [W2|resW2] -> h2(bf16) + res(f32), + attn2 dots
__global__ __launch_bounds__(256) void k_gemm2(
    const unsigned short* __restrict__ Ah, const unsigned short* __restrict__ Al,
    const unsigned short* __restrict__ Bh, const unsigned short* __restrict__ Bl,
    unsigned short* __restrict__ h2b, float* __restrict__ resf,
    const float* __restrict__ as2, const float* __restrict__ ad2,
    float* __restrict__ asrc2, float* __restrict__ adst2){
  __shared__ unsigned short lds[4*64*LSTR];
  gemm_tile(lds, blockIdx.x & 7, blockIdx.x >> 3, Ah, Al, Bh, Bl, h2b, resf,
            as2, ad2, asrc2, adst2, 2);
}

// layer-1: flash-style single-sweep dual segment-softmax + aggregation (bf16 hpre gather) + bias + ELU
__global__ __launch_bounds__(128) void k_layer1(const unsigned* __restrict__ rowptr, const unsigned* __restrict__ csr_src,
    const float* __restrict__ mwc, const float* __restrict__ asrc, const float* __restrict__ adst,
    const unsigned short* __restrict__ hpreb, const float* __restrict__ b1,
    unsigned short* __restrict__ h1h, unsigned short* __restrict__ h1l){
  int n = blockIdx.x;
  int tid = threadIdx.x, lane = tid&63, wv = tid>>6;
  unsigned base = rowptr[n], deg = rowptr[n+1]-base;
  __shared__ float a1s[128][9];
  __shared__ float a2s[128][9];
  __shared__ unsigned ssrc[128];
  __shared__ float red1[2][8], red2[2][8];
  __shared__ float snm1[8], snm2[8], sscl1[8], sscl2[8];
  __shared__ float sS1[8], sS2[8], sM1[8], sM2[8];
  __shared__ float adsts[8];
  if(tid<8){ adsts[tid]=adst[n*H1+tid]; sM1[tid]=-3.0e38f; sM2[tid]=-3.0e38f; sS1[tid]=0.f; sS2[tid]=0.f; }
  __syncthreads();
  int h = tid>>4;
  float4 acc1={0.f,0.f,0.f,0.f}, acc2={0.f,0.f,0.f,0.f};
  for(unsigned c0=0;c0<deg;c0+=128){
    int csz = (int)min(128u, deg-c0);
    bool act = (tid < csz);
    float el[8], em[8];
    if(act){
      unsigned s = csr_src[base+c0+tid];
      ssrc[tid]=s;
      float mwv = mwc[base+c0+tid];
      const float4 a0v = *(const float4*)&asrc[s*H1];
      const float4 a1v = *(const float4*)&asrc[s*H1+4];
      float as8[8]={a0v.x,a0v.y,a0v.z,a0v.w,a1v.x,a1v.y,a1v.z,a1v.w};
#pragma unroll
      for(int hh=0;hh<8;hh++){
        float ev = as8[hh]+adsts[hh];
        el[hh] = ev>=0.f? ev : 0.2f*ev;
        float evm = ev*mwv;
        em[hh] = evm>=0.f? evm : 0.2f*evm;
      }
    } else {
#pragma unroll
      for(int hh=0;hh<8;hh++){ el[hh]=-3.0e38f; em[hh]=-3.0e38f; }
    }
    float mx1[8], mx2[8];
#pragma unroll
    for(int hh=0;hh<8;hh++){ mx1[hh]=wredMaxf(el[hh]); mx2[hh]=wredMaxf(em[hh]); }
    if(lane==0){
#pragma unroll
      for(int hh=0;hh<8;hh++){ red1[wv][hh]=mx1[hh]; red2[wv][hh]=mx2[hh]; }
    }
    __syncthreads();
    if(tid<8){
      float cm1 = fmaxf(red1[0][tid], red1[1][tid]);
      float cm2 = fmaxf(red2[0][tid], red2[1][tid]);
      float nm1 = fmaxf(sM1[tid], cm1), nm2 = fmaxf(sM2[tid], cm2);
      sscl1[tid] = expf(sM1[tid]-nm1); sscl2[tid] = expf(sM2[tid]-nm2);
      snm1[tid]=nm1; snm2[tid]=nm2;
      sM1[tid]=nm1;  sM2[tid]=nm2;
    }
    __syncthreads();
    float s1l[8], s2l[8];
#pragma unroll
    for(int hh=0;hh<8;hh++){
      float a1v = act? expf(el[hh]-snm1[hh]) : 0.f;
      float a2v = act? expf(em[hh]-snm2[hh]) : 0.f;
      if(act){ a1s[tid][hh]=a1v; a2s[tid][hh]=a2v; }
      s1l[hh]=a1v; s2l[hh]=a2v;
    }
#pragma unroll
    for(int hh=0;hh<8;hh++){ s1l[hh]=wredSumf(s1l[hh]); s2l[hh]=wredSumf(s2l[hh]); }
    if(lane==0){
#pragma unroll
      for(int hh=0;hh<8;hh++){ red1[wv][hh]=s1l[hh]; red2[wv][hh]=s2l[hh]; }
    }
    __syncthreads();
    if(tid<8){
      sS1[tid] = sS1[tid]*sscl1[tid] + red1[0][tid]+red1[1][tid];
      sS2[tid] = sS2[tid]*sscl2[tid] + red2[0][tid]+red2[1][tid];
    }
    {
      float sc1 = sscl1[h], sc2 = sscl2[h];
      acc1.x*=sc1; acc1.y*=sc1; acc1.z*=sc1; acc1.w*=sc1;
      acc2.x*=sc2; acc2.y*=sc2; acc2.z*=sc2; acc2.w*=sc2;
    }
    for(int i0=0;i0<csz;i0+=8){
      int jn = min(8, csz-i0);
      unsigned sj[8]; float a1j[8], a2j[8];
#pragma unroll
      for(int j=0;j<8;j++){
        int ii = (j<jn)? i0+j : i0;
        sj[j]=ssrc[ii]; a1j[j]=a1s[ii][h]; a2j[j]=a2s[ii][h];
      }
      ushort4 hq[8];
#pragma unroll
      for(int j=0;j<8;j++) hq[j] = *(const ushort4*)&hpreb[(size_t)sj[j]*C1 + tid*4];
#pragma unroll
      for(int j=0;j<8;j++){
        float w1 = (j<jn)? a1j[j] : 0.f;
        float w2 = (j<jn)? a2j[j] : 0.f;
        float hx = __uint_as_float((unsigned)hq[j].x<<16);
        float hy = __uint_as_float((unsigned)hq[j].y<<16);
        float hz = __uint_as_float((unsigned)hq[j].z<<16);
        float hw = __uint_as_float((unsigned)hq[j].w<<16);
        acc1.x += w1*hx; acc1.y += w1*hy; acc1.z += w1*hz; acc1.w += w1*hw;
        acc2.x += w2*hx; acc2.y += w2*hy; acc2.z += w2*hz; acc2.w += w2*hw;
      }
    }
    __syncthreads();
  }
  float r1 = 0.5f/(sS1[h]+1e-16f), r2 = 0.5f/(sS2[h]+1e-16f);
  int cc = tid*4;
  const float4 bv = *(const float4*)&b1[cc];
  float o[4];
  float vx = acc1.x*r1 + acc2.x*r2 + bv.x; o[0] = vx>0.f? vx : expm1f(vx);
  float vy = acc1.y*r1 + acc2.y*r2 + bv.y; o[1] = vy>0.f? vy : expm1f(vy);
  float vz = acc1.z*r1 + acc2.z*r2 + bv.z; o[2] = vz>0.f? vz : expm1f(vz);
  float vw = acc1.w*r1 + acc2.w*r2 + bv.w; o[3] = vw>0.f? vw : expm1f(vw);
  unsigned short hh4[4], ll4[4];
#pragma unroll
  for(int j=0;j<4;j++) bfsplit(o[j], hh4[j], ll4[j]);
  *(ushort4*)&h1h[(size_t)n*KP + cc] = *(ushort4*)hh4;
  *(ushort4*)&h1l[(size_t)n*KP + cc] = *(ushort4*)ll4;
}

// layer-2: flash single-sweep; h2 gathered as bf16; res f32 stride 256
__global__ __launch_bounds__(64) void k_layer2(const unsigned* __restrict__ rowptr, const unsigned* __restrict__ csr_src,
    const float* __restrict__ mwc, const float* __restrict__ asrc, const float* __restrict__ adst,
    const unsigned short* __restrict__ h2b, const float* __restrict__ res,
    const float* __restrict__ b2, float* __restrict__ out){
  int n = blockIdx.x; int lane = threadIdx.x;
  unsigned base = rowptr[n], deg = rowptr[n+1]-base;
  __shared__ float a1s[64], a2s[64];
  __shared__ unsigned ssrc[64];
  float ad = adst[n];
  float M1=-3.0e38f, M2=-3.0e38f, S1=0.f, S2=0.f;
  float4 acc1={0.f,0.f,0.f,0.f}, acc2={0.f,0.f,0.f,0.f};
  for(unsigned c0=0;c0<deg;c0+=64){
    int csz = (int)min(64u, deg-c0);
    bool act = (lane < csz);
    float el=-3.0e38f, em=-3.0e38f;
    if(act){
      unsigned s = csr_src[base+c0+lane];
      ssrc[lane]=s;
      float mwv = mwc[base+c0+lane];
      float ev = asrc[s] + ad;
      el = ev>=0.f? ev : 0.2f*ev;
      float evm = ev*mwv;
      em = evm>=0.f? evm : 0.2f*evm;
    }
    float nm1 = fmaxf(M1, wredMaxf(el));
    float nm2 = fmaxf(M2, wredMaxf(em));
    float sc1 = expf(M1-nm1), sc2 = expf(M2-nm2);
    M1=nm1; M2=nm2;
    float a1 = act? expf(el-nm1) : 0.f;
    float a2 = act? expf(em-nm2) : 0.f;
    if(act){ a1s[lane]=a1; a2s[lane]=a2; }
    S1 = S1*sc1 + wredSumf(a1);
    S2 = S2*sc2 + wredSumf(a2);
    acc1.x*=sc1; acc1.y*=sc1; acc1.z*=sc1; acc1.w*=sc1;
    acc2.x*=sc2; acc2.y*=sc2; acc2.z*=sc2; acc2.w*=sc2;
    __syncthreads();
    for(int i0=0;i0<csz;i0+=8){
      int jn = min(8, csz-i0);
      unsigned sj[8]; float a1j[8], a2j[8];
#pragma unroll
      for(int j=0;j<8;j++){
        int ii = (j<jn)? i0+j : i0;
        sj[j]=ssrc[ii]; a1j[j]=a1s[ii]; a2j[j]=a2s[ii];
      }
      ushort4 hq[8];
#pragma unroll
      for(int j=0;j<8;j++) hq[j] = *(const ushort4*)&h2b[(size_t)sj[j]*C2 + lane*4];
#pragma unroll
      for(int j=0;j<8;j++){
        float w1 = (j<jn)? a1j[j] : 0.f;
        float w2 = (j<jn)? a2j[j] : 0.f;
        float hx = __uint_as_float((unsigned)hq[j].x<<16);
        float hy = __uint_as_float((unsigned)hq[j].y<<16);
        float hz = __uint_as_float((unsigned)hq[j].z<<16);
        float hw = __uint_as_float((unsigned)hq[j].w<<16);
        acc1.x += w1*hx; acc1.y += w1*hy; acc1.z += w1*hz; acc1.w += w1*hw;
        acc2.x += w2*hx; acc2.y += w2*hy; acc2.z += w2*hz; acc2.w += w2*hw;
      }
    }
    __syncthreads();
  }
  float r1 = 0.5f/(S1+1e-16f), r2 = 0.5f/(S2+1e-16f);
  int cc = lane*4;
  const float4 rv = *(const float4*)&res[(size_t)n*C2 + cc];
  const float4 bv = *(const float4*)&b2[cc];
  float4 o = {acc1.x*r1 + acc2.x*r2 + rv.x + bv.x,
              acc1.y*r1 + acc2.y*r2 + rv.y + bv.y,
              acc1.z*r1 + acc2.z*r2 + rv.z + bv.z,
              acc1.w*r1 + acc2.w*r2 + rv.w + bv.w};
  *(float4*)&out[(size_t)n*C2 + cc] = o;
}

extern "C" void kernel_launch(void* const* d_in, const int* in_sizes, int n_in,
                              void* d_out, int out_size, void* d_ws, size_t ws_size,
                              hipStream_t stream) {
  const float* x    = (const float*)d_in[0];
  const int*   ei32 = (const int*)d_in[1];
  const float* W1   = (const float*)d_in[2];
  const float* as1  = (const float*)d_in[3];
  const float* ad1  = (const float*)d_in[4];
  const float* b1   = (const float*)d_in[5];
  const float* W2   = (const float*)d_in[6];
  const float* as2  = (const float*)d_in[7];
  const float* ad2  = (const float*)d_in[8];
  const float* b2   = (const float*)d_in[9];
  const float* resW2= (const float*)d_in[10];
  float* out = (float*)d_out;

  char* p = (char*)d_ws;
  auto alloc = [&](size_t b){ void* r=(void*)p; p += (b + 255) & ~(size_t)255; return r; };
  // zero-init region: rowbits, colbits, cnt, fill, asrc1, adst1, asrc2, adst2 — contiguous
  unsigned* rowbits = (unsigned*)alloc((size_t)NN*NWORDS*4);   // 2MB
  unsigned* colbits = (unsigned*)alloc((size_t)NN*NWORDS*4);   // 2MB
  unsigned* cnt     = (unsigned*)alloc(NN*4);
  unsigned* fill    = (unsigned*)alloc(NN*4);
  float* asrc1= (float*)alloc(NN*H1*4);
  float* adst1= (float*)alloc(NN*H1*4);
  float* asrc2= (float*)alloc(NN*4);
  float* adst2= (float*)alloc(NN*4);
  size_t zbytes = (size_t)(p - (char*)rowbits);
  unsigned* rowptr  = (unsigned*)alloc((NN+4)*4);
  float* v1 = (float*)alloc(NN*4);
  float* v2 = (float*)alloc(NN*4);
  float* v3 = (float*)alloc(NN*4);
  unsigned* csr_src = (unsigned*)alloc((size_t)EP*4);
  float* mwc  = (float*)alloc((size_t)EP*4);
  unsigned short* xsh = (unsigned short*)alloc((size_t)NN*KP*2);
  unsigned short* xsl = (unsigned short*)alloc((size_t)NN*KP*2);
  unsigned short* bt1h= (unsigned short*)alloc((size_t)C1*KP*2);
  unsigned short* bt1l= (unsigned short*)alloc((size_t)C1*KP*2);
  unsigned short* bt2h= (unsigned short*)alloc((size_t)C1*KP*2);  // stacked W2|resW2
  unsigned short* bt2l= (unsigned short*)alloc((size_t)C1*KP*2);
  unsigned short* hpreb = (unsigned short*)alloc((size_t)NN*C1*2); // 4MB bf16
  unsigned short* h1h = (unsigned short*)alloc((size_t)NN*KP*2);
  unsigned short* h1l = (unsigned short*)alloc((size_t)NN*KP*2);
  unsigned short* h2b = (unsigned short*)alloc((size_t)NN*C2*2);   // 2MB bf16
  float* res  = (float*)alloc((size_t)NN*C2*4);                    // 4MB f32

  hipMemsetAsync(rowbits, 0, zbytes, stream);

  k_build_cvt<<<2576,256,0,stream>>>(ei32, rowbits, colbits, cnt,
                                     x, xsh, xsl, W1, W2, resW2, bt1h, bt1l, bt2h, bt2l);
  k_scan_deg<<<1+NN/4,256,0,stream>>>(cnt, rowptr, rowbits, v1);
  k_fill_mv<<<528+NN/4,256,0,stream>>>(ei32, rowptr, fill, csr_src, rowbits, v1, v2);
  k_mv2<<<NN/4,256,0,stream>>>(rowbits, v2, v3);

  k_gemm1_motif<<<512+NN/4,256,0,stream>>>(xsh, xsl, bt1h, bt1l, hpreb, as1, ad1, asrc1, adst1,
                                           rowbits, colbits, rowptr, csr_src, v3, mwc);
  k_layer1<<<NN,128,0,stream>>>(rowptr, csr_src, mwc, asrc1, adst1, hpreb, b1, h1h, h1l);

  k_gemm2<<<512,256,0,stream>>>(h1h, h1l, bt2h, bt2l, h2b, res, as2, ad2, asrc2, adst2);
  k_layer2<<<NN,64,0,stream>>>(rowptr, csr_src, mwc, asrc2, adst2, h2b, res, b2, out);
}

// Round 12
// 241.148 us; speedup vs baseline: 1.0264x; 1.0264x over previous
//
#include <hip/hip_runtime.h>
#include <hip/hip_bf16.h>
#include <math.h>

#define NN 4096
#define EE 131072
#define EP (EE + NN)     // 135168 edges incl. self loops
#define C1 512
#define H1 8
#define C2 256
#define NWORDS 128       // 4096 bits / 32
#define KP 520           // padded K stride for bf16 split buffers (mult of 8)

typedef __attribute__((ext_vector_type(8))) short bf16x8;
typedef __attribute__((ext_vector_type(4))) float f32x4;

__device__ __forceinline__ float wredMaxf(float v){
#pragma unroll
  for(int o=32;o;o>>=1) v = fmaxf(v, __shfl_xor(v,o));
  return v;
}
__device__ __forceinline__ float wredSumf(float v){
#pragma unroll
  for(int o=32;o;o>>=1) v += __shfl_xor(v,o);
  return v;
}
__device__ __forceinline__ int wredSumi(int v){
#pragma unroll
  for(int o=32;o;o>>=1) v += __shfl_xor(v,o);
  return v;
}

__device__ __forceinline__ void bfsplit(float v, unsigned short& h, unsigned short& l){
  unsigned bits = __float_as_uint(v);
  h = (unsigned short)(bits>>16);
  float hf = __uint_as_float(bits & 0xFFFF0000u);
  float lo = v - hf;                       // exact
  l = (unsigned short)(__float_as_uint(lo)>>16);
}

__device__ __forceinline__ unsigned short f2bf_rne(float v){
  unsigned b = __float_as_uint(v);
  return (unsigned short)((b + 0x7FFFu + ((b>>16)&1u)) >> 16);
}

// int64 edge_index => high words of first 8 entries are all zero.
__device__ __forceinline__ int detect_mode(const int* __restrict__ ei32){
  unsigned nz = 0;
#pragma unroll
  for(int i=1;i<16;i+=2) nz |= (unsigned)ei32[i];
  return nz != 0;   // 1 => int32, 0 => int64
}

__device__ __forceinline__ void edge_sd(const int* ei32, int mode, int e, int& s, int& d){
  if(e < EE){
    if(mode==0){ s = ei32[2*e]; d = ei32[2*(EE+e)]; }
    else       { s = ei32[e];   d = ei32[EE+e]; }
  } else { s = e - EE; d = s; }
}

// blocks 0..527: edge bitmaps+counts; 528..1551: cvtA; 1552..2575: cvtB (all independent)
__global__ __launch_bounds__(256) void k_build_cvt(const int* __restrict__ ei32,
    unsigned* __restrict__ rowbits, unsigned* __restrict__ colbits, unsigned* __restrict__ cnt,
    const float* __restrict__ X, unsigned short* __restrict__ xh, unsigned short* __restrict__ xl,
    const float* __restrict__ W1f, const float* __restrict__ W2f, const float* __restrict__ Wrf,
    unsigned short* __restrict__ b1h, unsigned short* __restrict__ b1l,
    unsigned short* __restrict__ b2h, unsigned short* __restrict__ b2l){
  int b = blockIdx.x, t = threadIdx.x;
  if(b < 528){
    int e = b*256 + t;
    if(e >= EP) return;
    int m = detect_mode(ei32), s, d;
    edge_sd(ei32, m, e, s, d);
    atomicOr(&rowbits[s*NWORDS + (d>>5)], 1u<<(d&31));
    atomicOr(&colbits[d*NWORDS + (s>>5)], 1u<<(s&31));
    atomicAdd(&cnt[d], 1u);
  } else if(b < 1552){
    int e = (b-528)*256 + t;
    int row = e >> 6;
    int c0 = (e & 63) * 8;
    const float4 v0 = *(const float4*)&X[(size_t)row*C1 + c0];
    const float4 v1q = *(const float4*)&X[(size_t)row*C1 + c0 + 4];
    float vv[8] = {v0.x,v0.y,v0.z,v0.w,v1q.x,v1q.y,v1q.z,v1q.w};
    unsigned short h[8], l[8];
#pragma unroll
    for(int j=0;j<8;j++) bfsplit(vv[j], h[j], l[j]);
    *(bf16x8*)&xh[(size_t)row*KP + c0] = *(bf16x8*)h;
    *(bf16x8*)&xl[(size_t)row*KP + c0] = *(bf16x8*)l;
  } else {
    int blk = b - 1552;
    const float* W; int N, n, nrow; unsigned short *bh, *bl;
    if(blk < 512){ W=W1f; N=512; n=blk;     nrow=n;     bh=b1h; bl=b1l; }
    else if(blk < 768){ W=W2f; N=256; n=blk-512; nrow=n;     bh=b2h; bl=b2l; }
    else { W=Wrf; N=256; n=blk-768; nrow=n+256; bh=b2h; bl=b2l; }
    int k = t*2;
    float a = W[(size_t)k*N + n];
    float bb = W[(size_t)(k+1)*N + n];
    unsigned short h0,l0,h1,l1;
    bfsplit(a,h0,l0); bfsplit(bb,h1,l1);
    unsigned short hp[2]={h0,h1}, lp[2]={l0,l1};
    *(unsigned int*)&bh[(size_t)nrow*KP + k] = *(unsigned int*)hp;
    *(unsigned int*)&bl[(size_t)nrow*KP + k] = *(unsigned int*)lp;
  }
}

// block 0: exclusive scan of cnt -> rowptr; blocks 1..1024: v1 = popc rows (distinct out-deg)
__global__ __launch_bounds__(256) void k_scan_deg(const unsigned* __restrict__ cnt, unsigned* __restrict__ rowptr,
    const unsigned* __restrict__ rowbits, float* __restrict__ v1){
  int t = threadIdx.x;
  if(blockIdx.x == 0){
    __shared__ unsigned part[256];
    unsigned loc[16]; unsigned s = 0;
#pragma unroll
    for(int i=0;i<16;i++){ loc[i]=cnt[t*16+i]; s+=loc[i]; }
    part[t]=s; __syncthreads();
    for(int off=1;off<256;off<<=1){
      unsigned v = (t>=off)? part[t-off] : 0u;
      __syncthreads();
      part[t]+=v;
      __syncthreads();
    }
    unsigned run = (t==0)? 0u : part[t-1];
#pragma unroll
    for(int i=0;i<16;i++){ rowptr[t*16+i]=run; run+=loc[i]; }
    if(t==255) rowptr[NN]=run;
  } else {
    int node = (blockIdx.x-1)*4 + (t>>6);
    int lane = t & 63;
    unsigned w0 = rowbits[node*NWORDS + 2*lane];
    unsigned w1 = rowbits[node*NWORDS + 2*lane + 1];
    int c = __popc(w0) + __popc(w1);
    c = wredSumi(c);
    if(lane==0) v1[node] = (float)c;
  }
}

// blocks 0..527: CSR fill; blocks 528..1551: v2 = A @ v1
__global__ __launch_bounds__(256) void k_fill_mv(const int* __restrict__ ei32,
    const unsigned* __restrict__ rowptr, unsigned* __restrict__ fill, unsigned* __restrict__ csr_src,
    const unsigned* __restrict__ rowbits, const float* __restrict__ v1, float* __restrict__ v2){
  int t = threadIdx.x;
  if(blockIdx.x < 528){
    int e = blockIdx.x*256 + t;
    if(e >= EP) return;
    int m = detect_mode(ei32), s, d;
    edge_sd(ei32, m, e, s, d);
    unsigned pos = rowptr[d] + atomicAdd(&fill[d], 1u);
    csr_src[pos]=(unsigned)s;
  } else {
    int node = (blockIdx.x-528)*4 + (t>>6);
    int lane = t & 63;
    float sum = 0.f;
    unsigned w = rowbits[node*NWORDS + 2*lane]; int b0 = lane*64;
    while(w){ int b=__ffs(w)-1; sum += v1[b0+b]; w &= w-1; }
    w = rowbits[node*NWORDS + 2*lane + 1]; b0 = lane*64 + 32;
    while(w){ int b=__ffs(w)-1; sum += v1[b0+b]; w &= w-1; }
    sum = wredSumf(sum);
    if(lane==0) v2[node] = sum;
  }
}

// v3 = A @ v2
__global__ __launch_bounds__(256) void k_mv2(const unsigned* __restrict__ rowbits,
    const float* __restrict__ v2, float* __restrict__ v3){
  int node = blockIdx.x*4 + (threadIdx.x>>6);
  int lane = threadIdx.x & 63;
  float sum = 0.f;
  unsigned w = rowbits[node*NWORDS + 2*lane]; int b0 = lane*64;
  while(w){ int b=__ffs(w)-1; sum += v2[b0+b]; w &= w-1; }
  w = rowbits[node*NWORDS + 2*lane + 1]; b0 = lane*64 + 32;
  while(w){ int b=__ffs(w)-1; sum += v2[b0+b]; w &= w-1; }
  sum = wredSumf(sum);
  if(lane==0) v3[node] = sum;
}

// ---- split-bf16 MFMA 64x64 tile body; K=512, BK=64, reg-prefetch (R10-proven form).
// amode=1: bf16 C (stride C1) + 8-head attn dots.  amode=2: cols<256 -> bf16 h2b (stride C2)
// + 1-head attn dots; cols>=256 -> f32 resf.
__device__ __forceinline__ void gemm_tile(unsigned short* lds, int bx, int by,
    const unsigned short* __restrict__ Ah, const unsigned short* __restrict__ Al,
    const unsigned short* __restrict__ Bh, const unsigned short* __restrict__ Bl,
    unsigned short* __restrict__ Cb, float* __restrict__ resf,
    const float* __restrict__ aS, const float* __restrict__ aD,
    float* __restrict__ oS, float* __restrict__ oD, int amode){
  unsigned short* Ahs = lds;             // [64][72]
  unsigned short* Als = lds + 64*72;
  unsigned short* Bhs = lds + 2*64*72;
  unsigned short* Bls = lds + 3*64*72;
  int bm = by*64, bn = bx*64;
  int t = threadIdx.x, lane = t&63, w = t>>6;
  int wm = (w>>1)*32, wn = (w&1)*32;
  f32x4 acc[2][2];
#pragma unroll
  for(int i=0;i<2;i++)
#pragma unroll
    for(int j=0;j<2;j++) acc[i][j] = (f32x4){0.f,0.f,0.f,0.f};
  int sm = t>>2, sk = (t&3)*16;
  const unsigned short* pAh = &Ah[(size_t)(bm+sm)*KP + sk];
  const unsigned short* pAl = &Al[(size_t)(bm+sm)*KP + sk];
  const unsigned short* pBh = &Bh[(size_t)(bn+sm)*KP + sk];
  const unsigned short* pBl = &Bl[(size_t)(bn+sm)*KP + sk];
  int fr = lane&15, kg = lane>>4;
  bf16x8 rah0 = *(const bf16x8*)(pAh), rah1 = *(const bf16x8*)(pAh+8);
  bf16x8 ral0 = *(const bf16x8*)(pAl), ral1 = *(const bf16x8*)(pAl+8);
  bf16x8 rbh0 = *(const bf16x8*)(pBh), rbh1 = *(const bf16x8*)(pBh+8);
  bf16x8 rbl0 = *(const bf16x8*)(pBl), rbl1 = *(const bf16x8*)(pBl+8);
  *(bf16x8*)&Ahs[sm*72+sk] = rah0; *(bf16x8*)&Ahs[sm*72+sk+8] = rah1;
  *(bf16x8*)&Als[sm*72+sk] = ral0; *(bf16x8*)&Als[sm*72+sk+8] = ral1;
  *(bf16x8*)&Bhs[sm*72+sk] = rbh0; *(bf16x8*)&Bhs[sm*72+sk+8] = rbh1;
  *(bf16x8*)&Bls[sm*72+sk] = rbl0; *(bf16x8*)&Bls[sm*72+sk+8] = rbl1;
  __syncthreads();
  for(int k0=0;k0<C1;k0+=64){
    int kn = k0+64;
    if(kn<C1){
      rah0 = *(const bf16x8*)(pAh+kn); rah1 = *(const bf16x8*)(pAh+kn+8);
      ral0 = *(const bf16x8*)(pAl+kn); ral1 = *(const bf16x8*)(pAl+kn+8);
      rbh0 = *(const bf16x8*)(pBh+kn); rbh1 = *(const bf16x8*)(pBh+kn+8);
      rbl0 = *(const bf16x8*)(pBl+kn); rbl1 = *(const bf16x8*)(pBl+kn+8);
    }
#pragma unroll
    for(int ks=0;ks<64;ks+=32){
      bf16x8 fah[2], fal[2], fbh[2], fbl[2];
#pragma unroll
      for(int i=0;i<2;i++){
        fah[i] = *(bf16x8*)&Ahs[(wm + i*16 + fr)*72 + ks + kg*8];
        fal[i] = *(bf16x8*)&Als[(wm + i*16 + fr)*72 + ks + kg*8];
        fbh[i] = *(bf16x8*)&Bhs[(wn + i*16 + fr)*72 + ks + kg*8];
        fbl[i] = *(bf16x8*)&Bls[(wn + i*16 + fr)*72 + ks + kg*8];
      }
#pragma unroll
      for(int i=0;i<2;i++)
#pragma unroll
        for(int j=0;j<2;j++){
          acc[i][j] = __builtin_amdgcn_mfma_f32_16x16x32_bf16(fah[i], fbh[j], acc[i][j], 0,0,0);
          acc[i][j] = __builtin_amdgcn_mfma_f32_16x16x32_bf16(fah[i], fbl[j], acc[i][j], 0,0,0);
          acc[i][j] = __builtin_amdgcn_mfma_f32_16x16x32_bf16(fal[i], fbh[j], acc[i][j], 0,0,0);
        }
    }
    __syncthreads();
    if(kn<C1){
      *(bf16x8*)&Ahs[sm*72+sk] = rah0; *(bf16x8*)&Ahs[sm*72+sk+8] = rah1;
      *(bf16x8*)&Als[sm*72+sk] = ral0; *(bf16x8*)&Als[sm*72+sk+8] = ral1;
      *(bf16x8*)&Bhs[sm*72+sk] = rbh0; *(bf16x8*)&Bhs[sm*72+sk+8] = rbh1;
      *(bf16x8*)&Bls[sm*72+sk] = rbl0; *(bf16x8*)&Bls[sm*72+sk+8] = rbl1;
    }
    __syncthreads();
  }
#pragma unroll
  for(int i=0;i<2;i++)
#pragma unroll
    for(int j=0;j<2;j++){
      int gr = bm + wm + i*16 + kg*4;
      int gc = bn + wn + j*16 + fr;
      if(amode==1){
#pragma unroll
        for(int e=0;e<4;e++)
          Cb[(size_t)(gr+e)*C1 + gc] = f2bf_rne(acc[i][j][e]);
      } else {
        if(gc < 256){
#pragma unroll
          for(int e=0;e<4;e++)
            Cb[(size_t)(gr+e)*C2 + gc] = f2bf_rne(acc[i][j][e]);
        } else {
#pragma unroll
          for(int e=0;e<4;e++)
            resf[(size_t)(gr+e)*C2 + gc - 256] = acc[i][j][e];
        }
      }
    }
  bool do_attn = (amode==1) || (bn < 256);
  if(do_attn){
    float p1[2][4], p2[2][4];
#pragma unroll
    for(int i=0;i<2;i++)
#pragma unroll
      for(int e=0;e<4;e++){ p1[i][e]=0.f; p2[i][e]=0.f; }
#pragma unroll
    for(int j=0;j<2;j++){
      int col = bn + wn + j*16 + fr;
      float a1c = aS[col], a2c = aD[col];
#pragma unroll
      for(int i=0;i<2;i++)
#pragma unroll
        for(int e=0;e<4;e++){ p1[i][e] += acc[i][j][e]*a1c; p2[i][e] += acc[i][j][e]*a2c; }
    }
#pragma unroll
    for(int o=1;o<16;o<<=1){
#pragma unroll
      for(int i=0;i<2;i++)
#pragma unroll
        for(int e=0;e<4;e++){ p1[i][e]+=__shfl_xor(p1[i][e],o); p2[i][e]+=__shfl_xor(p2[i][e],o); }
    }
    if(fr==0){
      int head = (amode==1)? (bn>>6) : 0;
      int hs = (amode==1)? H1 : 1;
#pragma unroll
      for(int i=0;i<2;i++)
#pragma unroll
        for(int e=0;e<4;e++){
          int row = bm + wm + i*16 + kg*4 + e;
          atomicAdd(&oS[row*hs + head], p1[i][e]);
          atomicAdd(&oD[row*hs + head], p2[i][e]);
        }
    }
  }
}

// XCD-locality swizzle for 8x64 GEMM grids: all 8 col-blocks of a row-panel land on one XCD.
// b = (by&7) + 8*bx + 64*(by>>3)  =>  by = (b&7) + 8*(b>>6), bx = (b>>3)&7   (bijective on [0,512))
__device__ __forceinline__ void unswizzle_g(int b, int& bx, int& by){
  by = (b&7) + ((b>>6)<<3);
  bx = (b>>3)&7;
}

// Fused: blocks 0..511 = GEMM1 (x@W1 -> hpre bf16, + attn1 dots);
// blocks 512..1535 = motif, ONE DST PER WAVE (4 dsts/block), 8-wide batched loads
__global__ __launch_bounds__(256) void k_gemm1_motif(
    const unsigned short* __restrict__ Ah, const unsigned short* __restrict__ Al,
    const unsigned short* __restrict__ Bh, const unsigned short* __restrict__ Bl,
    unsigned short* __restrict__ hpreb, const float* __restrict__ as1, const float* __restrict__ ad1,
    float* __restrict__ asrc1, float* __restrict__ adst1,
    const unsigned* __restrict__ rowbits, const unsigned* __restrict__ colbits,
    const unsigned* __restrict__ rowptr, const unsigned* __restrict__ csr_src,
    const float* __restrict__ v3, float* __restrict__ mwc){
  __shared__ union {
    unsigned short g[4*64*72];
    struct { unsigned short nbr[4][192]; int cntL[4]; } m;
  } sm;
  int b = blockIdx.x, t = threadIdx.x;
  if(b < 512){
    int bx, by; unswizzle_g(b, bx, by);
    gemm_tile(sm.g, bx, by, Ah, Al, Bh, Bl, hpreb, nullptr,
              as1, ad1, asrc1, adst1, 1);
    return;
  }
  int lane = t&63, wv = t>>6;
  int d = (b-512)*4 + wv;
  if(lane==0) sm.m.cntL[wv]=0;
  // in-neighbor list (per-wave; DS ops within a wave are program-ordered)
  {
    unsigned w = colbits[d*NWORDS + 2*lane]; int b0 = lane*64;
    while(w){ int bb=__ffs(w)-1; int pos=atomicAdd(&sm.m.cntL[wv],1); sm.m.nbr[wv][pos]=(unsigned short)(b0+bb); w&=w-1; }
    w = colbits[d*NWORDS + 2*lane + 1]; b0 = lane*64 + 32;
    while(w){ int bb=__ffs(w)-1; int pos=atomicAdd(&sm.m.cntL[wv],1); sm.m.nbr[wv][pos]=(unsigned short)(b0+bb); w&=w-1; }
  }
  __syncthreads();
  int m = sm.m.cntL[wv];
  unsigned gp[8][2];
#pragma unroll
  for(int p=0;p<8;p++){ gp[p][0]=0u; gp[p][1]=0u; }
  // accumulate phase: 8 neighbors per iteration (deep MLP batch to hide L2 latency)
  for(int t0=0;t0<m;t0+=8){
    unsigned xa[8], xb[8];
#pragma unroll
    for(int j=0;j<8;j++){
      int tt=t0+j;
      if(tt<m){ int l = sm.m.nbr[wv][tt]; xa[j]=colbits[l*NWORDS+2*lane]; xb[j]=colbits[l*NWORDS+2*lane+1]; }
      else    { xa[j]=0u; xb[j]=0u; }
    }
#pragma unroll
    for(int j=0;j<8;j++){
      unsigned c = xa[j];
#pragma unroll
      for(int p=0;p<8;p++){ unsigned cy = gp[p][0] & c; gp[p][0] ^= c; c = cy; }
      c = xb[j];
#pragma unroll
      for(int p=0;p<8;p++){ unsigned cy = gp[p][1] & c; gp[p][1] ^= c; c = cy; }
    }
  }
  // edge phase: 8 edges per iteration, 4 packed 2x16-bit wave reductions
  unsigned base = rowptr[d], deg = rowptr[d+1]-base;
  for(unsigned i0=0;i0<deg;i0+=8){
    unsigned sidx[8], ra[8], rb[8];
#pragma unroll
    for(int j=0;j<8;j++){
      unsigned ii = (i0+j < deg) ? (i0+j) : (deg-1);
      sidx[j] = csr_src[base+ii];
    }
#pragma unroll
    for(int j=0;j<8;j++){ ra[j]=rowbits[sidx[j]*NWORDS+2*lane]; rb[j]=rowbits[sidx[j]*NWORDS+2*lane+1]; }
    int sum[8];
#pragma unroll
    for(int j=0;j<8;j++){
      int s=0;
#pragma unroll
      for(int p=0;p<8;p++)
        s += (__popc(ra[j]&gp[p][0]) + __popc(rb[j]&gp[p][1])) << p;
      sum[j]=s;
    }
    int pk[4];
#pragma unroll
    for(int j=0;j<4;j++) pk[j] = sum[2*j] | (sum[2*j+1]<<16);
#pragma unroll
    for(int j=0;j<4;j++) pk[j] = wredSumi(pk[j]);
    if(lane==0){
#pragma unroll
      for(int j=0;j<8;j++){
        unsigned idx = i0+j;
        if(idx<deg){
          int ss = (j&1)? ((pk[j>>1]>>16)&0xFFFF) : (pk[j>>1]&0xFFFF);
          mwc[base+idx] = (float)ss / fmaxf(v3[csr_src[base+idx]], 1.0f);
        }
      }
    }
  }
}

// GEMM2 standalone: h1 @ [W2|resW2] -> h2(bf16) + res(f32), + attn2 dots
__global__ __launch_bounds__(256) void k_gemm2(
    const unsigned short* __restrict__ Ah, const unsigned short* __restrict__ Al,
    const unsigned short* __restrict__ Bh, const unsigned short* __restrict__ Bl,
    unsigned short* __restrict__ h2b, float* __restrict__ resf,
    const float* __restrict__ as2, const float* __restrict__ ad2,
    float* __restrict__ asrc2, float* __restrict__ adst2){
  __shared__ unsigned short lds[4*64*72];
  int bx, by; unswizzle_g(blockIdx.x, bx, by);
  gemm_tile(lds, bx, by, Ah, Al, Bh, Bl, h2b, resf,
            as2, ad2, asrc2, adst2, 2);
}

// layer-1: flash-style single-sweep dual segment-softmax + aggregation (bf16 hpre gather) + bias + ELU
__global__ __launch_bounds__(128) void k_layer1(const unsigned* __restrict__ rowptr, const unsigned* __restrict__ csr_src,
    const float* __restrict__ mwc, const float* __restrict__ asrc, const float* __restrict__ adst,
    const unsigned short* __restrict__ hpreb, const float* __restrict__ b1,
    unsigned short* __restrict__ h1h, unsigned short* __restrict__ h1l){
  int n = blockIdx.x;
  int tid = threadIdx.x, lane = tid&63, wv = tid>>6;
  unsigned base = rowptr[n], deg = rowptr[n+1]-base;
  __shared__ float a1s[128][9];
  __shared__ float a2s[128][9];
  __shared__ unsigned ssrc[128];
  __shared__ float red1[2][8], red2[2][8];
  __shared__ float snm1[8], snm2[8], sscl1[8], sscl2[8];
  __shared__ float sS1[8], sS2[8], sM1[8], sM2[8];
  __shared__ float adsts[8];
  if(tid<8){ adsts[tid]=adst[n*H1+tid]; sM1[tid]=-3.0e38f; sM2[tid]=-3.0e38f; sS1[tid]=0.f; sS2[tid]=0.f; }
  __syncthreads();
  int h = tid>>4;
  float4 acc1={0.f,0.f,0.f,0.f}, acc2={0.f,0.f,0.f,0.f};
  for(unsigned c0=0;c0<deg;c0+=128){
    int csz = (int)min(128u, deg-c0);
    bool act = (tid < csz);
    float el[8], em[8];
    if(act){
      unsigned s = csr_src[base+c0+tid];
      ssrc[tid]=s;
      float mwv = mwc[base+c0+tid];
      const float4 a0v = *(const float4*)&asrc[s*H1];
      const float4 a1v = *(const float4*)&asrc[s*H1+4];
      float as8[8]={a0v.x,a0v.y,a0v.z,a0v.w,a1v.x,a1v.y,a1v.z,a1v.w};
#pragma unroll
      for(int hh=0;hh<8;hh++){
        float ev = as8[hh]+adsts[hh];
        el[hh] = ev>=0.f? ev : 0.2f*ev;
        float evm = ev*mwv;
        em[hh] = evm>=0.f? evm : 0.2f*evm;
      }
    } else {
#pragma unroll
      for(int hh=0;hh<8;hh++){ el[hh]=-3.0e38f; em[hh]=-3.0e38f; }
    }
    float mx1[8], mx2[8];
#pragma unroll
    for(int hh=0;hh<8;hh++){ mx1[hh]=wredMaxf(el[hh]); mx2[hh]=wredMaxf(em[hh]); }
    if(lane==0){
#pragma unroll
      for(int hh=0;hh<8;hh++){ red1[wv][hh]=mx1[hh]; red2[wv][hh]=mx2[hh]; }
    }
    __syncthreads();
    if(tid<8){
      float cm1 = fmaxf(red1[0][tid], red1[1][tid]);
      float cm2 = fmaxf(red2[0][tid], red2[1][tid]);
      float nm1 = fmaxf(sM1[tid], cm1), nm2 = fmaxf(sM2[tid], cm2);
      sscl1[tid] = expf(sM1[tid]-nm1); sscl2[tid] = expf(sM2[tid]-nm2);
      snm1[tid]=nm1; snm2[tid]=nm2;
      sM1[tid]=nm1;  sM2[tid]=nm2;
    }
    __syncthreads();
    float s1l[8], s2l[8];
#pragma unroll
    for(int hh=0;hh<8;hh++){
      float a1v = act? expf(el[hh]-snm1[hh]) : 0.f;
      float a2v = act? expf(em[hh]-snm2[hh]) : 0.f;
      if(act){ a1s[tid][hh]=a1v; a2s[tid][hh]=a2v; }
      s1l[hh]=a1v; s2l[hh]=a2v;
    }
#pragma unroll
    for(int hh=0;hh<8;hh++){ s1l[hh]=wredSumf(s1l[hh]); s2l[hh]=wredSumf(s2l[hh]); }
    if(lane==0){
#pragma unroll
      for(int hh=0;hh<8;hh++){ red1[wv][hh]=s1l[hh]; red2[wv][hh]=s2l[hh]; }
    }
    __syncthreads();
    if(tid<8){
      sS1[tid] = sS1[tid]*sscl1[tid] + red1[0][tid]+red1[1][tid];
      sS2[tid] = sS2[tid]*sscl2[tid] + red2[0][tid]+red2[1][tid];
    }
    {
      float sc1 = sscl1[h], sc2 = sscl2[h];
      acc1.x*=sc1; acc1.y*=sc1; acc1.z*=sc1; acc1.w*=sc1;
      acc2.x*=sc2; acc2.y*=sc2; acc2.z*=sc2; acc2.w*=sc2;
    }
    for(int i0=0;i0<csz;i0+=8){
      int jn = min(8, csz-i0);
      unsigned sj[8]; float a1j[8], a2j[8];
#pragma unroll
      for(int j=0;j<8;j++){
        int ii = (j<jn)? i0+j : i0;
        sj[j]=ssrc[ii]; a1j[j]=a1s[ii][h]; a2j[j]=a2s[ii][h];
      }
      ushort4 hq[8];
#pragma unroll
      for(int j=0;j<8;j++) hq[j] = *(const ushort4*)&hpreb[(size_t)sj[j]*C1 + tid*4];
#pragma unroll
      for(int j=0;j<8;j++){
        float w1 = (j<jn)? a1j[j] : 0.f;
        float w2 = (j<jn)? a2j[j] : 0.f;
        float hx = __uint_as_float((unsigned)hq[j].x<<16);
        float hy = __uint_as_float((unsigned)hq[j].y<<16);
        float hz = __uint_as_float((unsigned)hq[j].z<<16);
        float hw = __uint_as_float((unsigned)hq[j].w<<16);
        acc1.x += w1*hx; acc1.y += w1*hy; acc1.z += w1*hz; acc1.w += w1*hw;
        acc2.x += w2*hx; acc2.y += w2*hy; acc2.z += w2*hz; acc2.w += w2*hw;
      }
    }
    __syncthreads();
  }
  float r1 = 0.5f/(sS1[h]+1e-16f), r2 = 0.5f/(sS2[h]+1e-16f);
  int cc = tid*4;
  const float4 bv = *(const float4*)&b1[cc];
  float o[4];
  float vx = acc1.x*r1 + acc2.x*r2 + bv.x; o[0] = vx>0.f? vx : expm1f(vx);
  float vy = acc1.y*r1 + acc2.y*r2 + bv.y; o[1] = vy>0.f? vy : expm1f(vy);
  float vz = acc1.z*r1 + acc2.z*r2 + bv.z; o[2] = vz>0.f? vz : expm1f(vz);
  float vw = acc1.w*r1 + acc2.w*r2 + bv.w; o[3] = vw>0.f? vw : expm1f(vw);
  unsigned short hh4[4], ll4[4];
#pragma unroll
  for(int j=0;j<4;j++) bfsplit(o[j], hh4[j], ll4[j]);
  *(ushort4*)&h1h[(size_t)n*KP + cc] = *(ushort4*)hh4;
  *(ushort4*)&h1l[(size_t)n*KP + cc] = *(ushort4*)ll4;
}

// layer-2: flash single-sweep; h2 gathered as bf16; res f32 stride 256
__global__ __launch_bounds__(64) void k_layer2(const unsigned* __restrict__ rowptr, const unsigned* __restrict__ csr_src,
    const float* __restrict__ mwc, const float* __restrict__ asrc, const float* __restrict__ adst,
    const unsigned short* __restrict__ h2b, const float* __restrict__ res,
    const float* __restrict__ b2, float* __restrict__ out){
  int n = blockIdx.x; int lane = threadIdx.x;
  unsigned base = rowptr[n], deg = rowptr[n+1]-base;
  __shared__ float a1s[64], a2s[64];
  __shared__ unsigned ssrc[64];
  float ad = adst[n];
  float M1=-3.0e38f, M2=-3.0e38f, S1=0.f, S2=0.f;
  float4 acc1={0.f,0.f,0.f,0.f}, acc2={0.f,0.f,0.f,0.f};
  for(unsigned c0=0;c0<deg;c0+=64){
    int csz = (int)min(64u, deg-c0);
    bool act = (lane < csz);
    float el=-3.0e38f, em=-3.0e38f;
    if(act){
      unsigned s = csr_src[base+c0+lane];
      ssrc[lane]=s;
      float mwv = mwc[base+c0+lane];
      float ev = asrc[s] + ad;
      el = ev>=0.f? ev : 0.2f*ev;
      float evm = ev*mwv;
      em = evm>=0.f? evm : 0.2f*evm;
    }
    float nm1 = fmaxf(M1, wredMaxf(el));
    float nm2 = fmaxf(M2, wredMaxf(em));
    float sc1 = expf(M1-nm1), sc2 = expf(M2-nm2);
    M1=nm1; M2=nm2;
    float a1 = act? expf(el-nm1) : 0.f;
    float a2 = act? expf(em-nm2) : 0.f;
    if(act){ a1s[lane]=a1; a2s[lane]=a2; }
    S1 = S1*sc1 + wredSumf(a1);
    S2 = S2*sc2 + wredSumf(a2);
    acc1.x*=sc1; acc1.y*=sc1; acc1.z*=sc1; acc1.w*=sc1;
    acc2.x*=sc2; acc2.y*=sc2; acc2.z*=sc2; acc2.w*=sc2;
    __syncthreads();
    for(int i0=0;i0<csz;i0+=8){
      int jn = min(8, csz-i0);
      unsigned sj[8]; float a1j[8], a2j[8];
#pragma unroll
      for(int j=0;j<8;j++){
        int ii = (j<jn)? i0+j : i0;
        sj[j]=ssrc[ii]; a1j[j]=a1s[ii]; a2j[j]=a2s[ii];
      }
      ushort4 hq[8];
#pragma unroll
      for(int j=0;j<8;j++) hq[j] = *(const ushort4*)&h2b[(size_t)sj[j]*C2 + lane*4];
#pragma unroll
      for(int j=0;j<8;j++){
        float w1 = (j<jn)? a1j[j] : 0.f;
        float w2 = (j<jn)? a2j[j] : 0.f;
        float hx = __uint_as_float((unsigned)hq[j].x<<16);
        float hy = __uint_as_float((unsigned)hq[j].y<<16);
        float hz = __uint_as_float((unsigned)hq[j].z<<16);
        float hw = __uint_as_float((unsigned)hq[j].w<<16);
        acc1.x += w1*hx; acc1.y += w1*hy; acc1.z += w1*hz; acc1.w += w1*hw;
        acc2.x += w2*hx; acc2.y += w2*hy; acc2.z += w2*hz; acc2.w += w2*hw;
      }
    }
    __syncthreads();
  }
  float r1 = 0.5f/(S1+1e-16f), r2 = 0.5f/(S2+1e-16f);
  int cc = lane*4;
  const float4 rv = *(const float4*)&res[(size_t)n*C2 + cc];
  const float4 bv = *(const float4*)&b2[cc];
  float4 o = {acc1.x*r1 + acc2.x*r2 + rv.x + bv.x,
              acc1.y*r1 + acc2.y*r2 + rv.y + bv.y,
              acc1.z*r1 + acc2.z*r2 + rv.z + bv.z,
              acc1.w*r1 + acc2.w*r2 + rv.w + bv.w};
  *(float4*)&out[(size_t)n*C2 + cc] = o;
}

extern "C" void kernel_launch(void* const* d_in, const int* in_sizes, int n_in,
                              void* d_out, int out_size, void* d_ws, size_t ws_size,
                              hipStream_t stream) {
  const float* x    = (const float*)d_in[0];
  const int*   ei32 = (const int*)d_in[1];
  const float* W1   = (const float*)d_in[2];
  const float* as1  = (const float*)d_in[3];
  const float* ad1  = (const float*)d_in[4];
  const float* b1   = (const float*)d_in[5];
  const float* W2   = (const float*)d_in[6];
  const float* as2  = (const float*)d_in[7];
  const float* ad2  = (const float*)d_in[8];
  const float* b2   = (const float*)d_in[9];
  const float* resW2= (const float*)d_in[10];
  float* out = (float*)d_out;

  char* p = (char*)d_ws;
  auto alloc = [&](size_t b){ void* r=(void*)p; p += (b + 255) & ~(size_t)255; return r; };
  // zero-init region: rowbits, colbits, cnt, fill, asrc1, adst1, asrc2, adst2 — contiguous
  unsigned* rowbits = (unsigned*)alloc((size_t)NN*NWORDS*4);   // 2MB
  unsigned* colbits = (unsigned*)alloc((size_t)NN*NWORDS*4);   // 2MB
  unsigned* cnt     = (unsigned*)alloc(NN*4);
  unsigned* fill    = (unsigned*)alloc(NN*4);
  float* asrc1= (float*)alloc(NN*H1*4);
  float* adst1= (float*)alloc(NN*H1*4);
  float* asrc2= (float*)alloc(NN*4);
  float* adst2= (float*)alloc(NN*4);
  size_t zbytes = (size_t)(p - (char*)rowbits);
  unsigned* rowptr  = (unsigned*)alloc((NN+4)*4);
  float* v1 = (float*)alloc(NN*4);
  float* v2 = (float*)alloc(NN*4);
  float* v3 = (float*)alloc(NN*4);
  unsigned* csr_src = (unsigned*)alloc((size_t)EP*4);
  float* mwc  = (float*)alloc((size_t)EP*4);
  unsigned short* xsh = (unsigned short*)alloc((size_t)NN*KP*2);
  unsigned short* xsl = (unsigned short*)alloc((size_t)NN*KP*2);
  unsigned short* bt1h= (unsigned short*)alloc((size_t)C1*KP*2);
  unsigned short* bt1l= (unsigned short*)alloc((size_t)C1*KP*2);
  unsigned short* bt2h= (unsigned short*)alloc((size_t)C1*KP*2);  // stacked W2|resW2
  unsigned short* bt2l= (unsigned short*)alloc((size_t)C1*KP*2);
  unsigned short* hpreb = (unsigned short*)alloc((size_t)NN*C1*2); // 4MB bf16
  unsigned short* h1h = (unsigned short*)alloc((size_t)NN*KP*2);
  unsigned short* h1l = (unsigned short*)alloc((size_t)NN*KP*2);
  unsigned short* h2b = (unsigned short*)alloc((size_t)NN*C2*2);   // 2MB bf16
  float* res  = (float*)alloc((size_t)NN*C2*4);                    // 4MB f32

  hipMemsetAsync(rowbits, 0, zbytes, stream);

  k_build_cvt<<<2576,256,0,stream>>>(ei32, rowbits, colbits, cnt,
                                     x, xsh, xsl, W1, W2, resW2, bt1h, bt1l, bt2h, bt2l);
  k_scan_deg<<<1+NN/4,256,0,stream>>>(cnt, rowptr, rowbits, v1);
  k_fill_mv<<<528+NN/4,256,0,stream>>>(ei32, rowptr, fill, csr_src, rowbits, v1, v2);
  k_mv2<<<NN/4,256,0,stream>>>(rowbits, v2, v3);

  k_gemm1_motif<<<512+NN/4,256,0,stream>>>(xsh, xsl, bt1h, bt1l, hpreb, as1, ad1, asrc1, adst1,
                                           rowbits, colbits, rowptr, csr_src, v3, mwc);
  k_layer1<<<NN,128,0,stream>>>(rowptr, csr_src, mwc, asrc1, adst1, hpreb, b1, h1h, h1l);

  k_gemm2<<<512,256,0,stream>>>(h1h, h1l, bt2h, bt2l, h2b, res, as2, ad2, asrc2, adst2);
  k_layer2<<<NN,64,0,stream>>>(rowptr, csr_src, mwc, asrc2, adst2, h2b, res, b2, out);
}